// Round 3
// baseline (12905.269 us; speedup 1.0000x reference)
//
#include <hip/hip_runtime.h>
#include <hip/hip_bf16.h>

#define NNODE 50000
#define NEDGE 500000
#define SZ    4096

typedef __attribute__((ext_vector_type(8))) short bf16x8;
typedef __attribute__((ext_vector_type(4))) float f32x4;

__device__ __forceinline__ float bits2f(unsigned short u) {
    return __uint_as_float(((unsigned)u) << 16);
}
__device__ __forceinline__ unsigned short f2bits(float f) {  // RNE fp32->bf16
    unsigned x = __float_as_uint(f);
    unsigned r = x + 0x7fffu + ((x >> 16) & 1u);
    return (unsigned short)(r >> 16);
}

// ---------------------------------------------------------------------------
// Unified MFMA GEMM. C[M,N] = act( [A1 | A2][M,Ka+Kb] @ B[K,N] + bias (+C) )
// A segments row-major, dtype per DT (0=bf16, 1=fp32); segment split Ka is a
// multiple of 64. Bt is bf16 PRE-TRANSPOSED [N][K]. Tile 64x64, BK=64,
// 4 waves; wave w computes rows w*16..w*16+15 x all 64 cols (4 mfma tiles).
// ---------------------------------------------------------------------------
template<int DT1, int DT2, int RELU, int SIG, int ACC, int OUTF32>
__global__ __launch_bounds__(256)
void mfma_gemm(const void* __restrict__ A1, const void* __restrict__ A2,
               const unsigned short* __restrict__ Bt, const float* __restrict__ bias,
               void* __restrict__ Cv, int M, int N, int Ka, int Kb)
{
    __shared__ unsigned short As[64][72];   // [m][k], 144B row stride (16B-mult)
    __shared__ unsigned short Bs[64][72];   // [n][k]
    const int tid = threadIdx.x;
    const int wave = tid >> 6, lane = tid & 63;
    const int m16 = lane & 15, quad = lane >> 4;
    const int row0 = blockIdx.y * 64, col0 = blockIdx.x * 64;
    const int K = Ka + Kb;

    f32x4 acc[4] = {};

    for (int k0 = 0; k0 < K; k0 += 64) {
        const bool s2 = (k0 >= Ka);
        const int dt = s2 ? DT2 : DT1;
        const int ld = s2 ? Kb : Ka;
        const int kb = s2 ? (k0 - Ka) : k0;
        if (dt == 0) {
            const unsigned short* src = (const unsigned short*)(s2 ? A2 : A1);
#pragma unroll
            for (int it = 0; it < 2; ++it) {
                int u = tid + it * 256;
                int m = u >> 3, c = (u & 7) * 8;
                int gm = row0 + m;
                uint4 v = make_uint4(0u, 0u, 0u, 0u);
                if (gm < M) v = *(const uint4*)(src + (size_t)gm * ld + kb + c);
                *(uint4*)&As[m][c] = v;
            }
        } else {
            const float* src = (const float*)(s2 ? A2 : A1);
#pragma unroll
            for (int it = 0; it < 4; ++it) {
                int u = tid + it * 256;
                int m = u >> 4, c = (u & 15) * 4;
                int gm = row0 + m;
                float4 v = make_float4(0.f, 0.f, 0.f, 0.f);
                if (gm < M) v = *(const float4*)(src + (size_t)gm * ld + kb + c);
                ushort4 w;
                w.x = f2bits(v.x); w.y = f2bits(v.y); w.z = f2bits(v.z); w.w = f2bits(v.w);
                *(ushort4*)&As[m][c] = w;
            }
        }
#pragma unroll
        for (int it = 0; it < 2; ++it) {
            int u = tid + it * 256;
            int n = u >> 3, c = (u & 7) * 8;
            uint4 v = *(const uint4*)(Bt + (size_t)(col0 + n) * K + k0 + c);
            *(uint4*)&Bs[n][c] = v;
        }
        __syncthreads();
#pragma unroll
        for (int ks = 0; ks < 2; ++ks) {
            bf16x8 a = *(const bf16x8*)&As[wave * 16 + m16][ks * 32 + quad * 8];
#pragma unroll
            for (int nt = 0; nt < 4; ++nt) {
                bf16x8 b = *(const bf16x8*)&Bs[nt * 16 + m16][ks * 32 + quad * 8];
                acc[nt] = __builtin_amdgcn_mfma_f32_16x16x32_bf16(a, b, acc[nt], 0, 0, 0);
            }
        }
        __syncthreads();
    }

#pragma unroll
    for (int nt = 0; nt < 4; ++nt) {
        int gc = col0 + nt * 16 + m16;
        float bv = bias[gc];
#pragma unroll
        for (int r = 0; r < 4; ++r) {
            int gm = row0 + wave * 16 + quad * 4 + r;
            if (gm < M) {
                size_t idx = (size_t)gm * N + gc;
                float v = acc[nt][r] + bv;
                if (ACC) v += OUTF32 ? ((float*)Cv)[idx] : bits2f(((unsigned short*)Cv)[idx]);
                if (RELU) v = fmaxf(v, 0.f);
                if (SIG)  v = 1.f / (1.f + __expf(-v));
                if (OUTF32) ((float*)Cv)[idx] = v;
                else        ((unsigned short*)Cv)[idx] = f2bits(v);
            }
        }
    }
}

// ---------------------------------------------------------------------------
// fp32 [R1+R2][Nn] (two stacked sources) -> bf16 [Nn][R1+R2], LDS-tiled.
// blockIdx.z = batch (relation); batch strides derived from R1,R2,Nn.
// ---------------------------------------------------------------------------
__global__ __launch_bounds__(256)
void transpose_cvt(const float* __restrict__ src1, const float* __restrict__ src2,
                   unsigned short* __restrict__ dst, int R1, int R2, int Nn)
{
    __shared__ float tile[32][33];
    const int R = R1 + R2;
    const int e = blockIdx.z;
    src1 += (size_t)e * R1 * Nn;
    if (src2) src2 += (size_t)e * R2 * Nn;
    dst += (size_t)e * Nn * R;
    const int r0 = blockIdx.x * 32, n0 = blockIdx.y * 32;
    const int lr = threadIdx.x >> 5, ln = threadIdx.x & 31;
#pragma unroll
    for (int i = 0; i < 4; ++i) {
        int r = r0 + lr + i * 8, n = n0 + ln;
        float v = 0.f;
        if (r < R && n < Nn) v = (r < R1) ? src1[(size_t)r * Nn + n]
                                          : src2[(size_t)(r - R1) * Nn + n];
        tile[lr + i * 8][ln] = v;
    }
    __syncthreads();
#pragma unroll
    for (int i = 0; i < 4; ++i) {
        int n = n0 + lr + i * 8, r = r0 + ln;
        if (n < Nn && r < R) dst[(size_t)n * R + r] = f2bits(tile[ln][lr + i * 8]);
    }
}

__global__ __launch_bounds__(256)
void cvt_f32_bf16(const float* __restrict__ src, unsigned short* __restrict__ dst, int n4)
{
    int i = blockIdx.x * 256 + threadIdx.x;
    if (i >= n4) return;
    float4 v = ((const float4*)src)[i];
    ushort4 w;
    w.x = f2bits(v.x); w.y = f2bits(v.y); w.z = f2bits(v.z); w.w = f2bits(v.w);
    ((ushort4*)dst)[i] = w;
}

// ---------------------------------------------------------------------------
// segment_max: pooled bf16 >= 0 (relu). atomicMax on int bits of fp32 agg;
// agg 0-init also implements the isneginf->0 rule. Skip non-positive values.
// ---------------------------------------------------------------------------
template<int F>
__global__ __launch_bounds__(256)
void scatter_max_k(const unsigned short* __restrict__ pooled, const int* __restrict__ sidx,
                   const int* __restrict__ didx, float* __restrict__ agg)
{
    const int CH = F / 8;
    long long tid = (long long)blockIdx.x * 256 + threadIdx.x;
    int e = (int)(tid / CH);
    if (e >= NEDGE) return;
    int c = ((int)(tid % CH)) * 8;
    int s = sidx[e], d = didx[e];
    uint4 raw = *(const uint4*)(pooled + (size_t)s * F + c);
    int* ab = (int*)(agg + (size_t)d * F + c);
    unsigned w[4] = {raw.x, raw.y, raw.z, raw.w};
#pragma unroll
    for (int i = 0; i < 4; ++i) {
        unsigned lo = w[i] & 0xffffu, hi = w[i] >> 16;
        if (lo && !(lo & 0x8000u)) atomicMax(ab + 2 * i,     (int)(lo << 16));
        if (hi && !(hi & 0x8000u)) atomicMax(ab + 2 * i + 1, (int)(hi << 16));
    }
}

__global__ __launch_bounds__(64)
void fake_k(const unsigned short* __restrict__ mirna, const float* __restrict__ noise,
            const int* __restrict__ t_p, const int* __restrict__ left_p,
            unsigned short* __restrict__ fake_bf, float* __restrict__ fake_out)
{
    int r = blockIdx.x, c = threadIdx.x;
    int t = *t_p, left = *left_p;
    int row = left + r;
    float x = bits2f(mirna[(size_t)row * 64 + c]);
    float s = fabsf(x);
#pragma unroll
    for (int off = 32; off > 0; off >>= 1) s += __shfl_down(s, off);
    s = __shfl(s, 0);
    float ab = 1.f;
    for (int i = 0; i <= t; ++i)
        ab *= (1.f - (1e-4f + (0.02f - 1e-4f) * ((float)i / 99.f)));
    float v = sqrtf(ab) * (x / fmaxf(s, 1e-12f)) + sqrtf(1.f - ab) * noise[(size_t)row * 64 + c];
    fake_bf[(size_t)r * 64 + c] = f2bits(v);
    fake_out[(size_t)r * 64 + c] = v;
}

// ---------------------------------------------------------------------------
extern "C" void kernel_launch(void* const* d_in, const int* in_sizes, int n_in,
                              void* d_out, int out_size, void* d_ws, size_t ws_size,
                              hipStream_t stream)
{
    const float* h0[3]    = {(const float*)d_in[0], (const float*)d_in[1], (const float*)d_in[2]};
    const float* Wpool[3] = {(const float*)d_in[3], (const float*)d_in[8],  (const float*)d_in[13]};
    const float* bpool[3] = {(const float*)d_in[4], (const float*)d_in[9],  (const float*)d_in[14]};
    const float* Wself[3] = {(const float*)d_in[5], (const float*)d_in[10], (const float*)d_in[15]};
    const float* bself[3] = {(const float*)d_in[6], (const float*)d_in[11], (const float*)d_in[16]};
    const float* Wneigh[3]= {(const float*)d_in[7], (const float*)d_in[12], (const float*)d_in[17]};
    const float* Adj   = (const float*)d_in[18];
    const float* noise = (const float*)d_in[19];
    const float* W1 = (const float*)d_in[20]; const float* b1 = (const float*)d_in[21];
    const float* W2 = (const float*)d_in[22]; const float* b2 = (const float*)d_in[23];
    const float* W3 = (const float*)d_in[24]; const float* b3 = (const float*)d_in[25];
    const float* W4 = (const float*)d_in[26]; const float* b4 = (const float*)d_in[27];
    const int* edges  = (const int*)d_in[28];
    const int* t_p    = (const int*)d_in[29];
    const int* left_p = (const int*)d_in[31];

    // workspace layout (bf16-element offsets); total ~122.9 MB
    unsigned short* ws = (unsigned short*)d_ws;
    const size_t P1 = 0, P2 = 98304, P3 = 122880;
    const size_t FU1 = 147456, FU2 = 245760, FU3 = 294912;
    const size_t W1T = 344064, W2T = 1409024, W3T = 1540096, W4T = 2064384;
    const size_t ADJ = 6258688;        // 4096*4096 bf16
    const size_t POOLED = 23035904;    // 50000*128 bf16
    const size_t AGGE = 29435904;      // 50000*128 fp32 (12.8M bf16-elems)
    const size_t HA = 42235904, HB = 51835904;
    float* agg = (float*)(ws + AGGE);
    unsigned short* fakef = ws + POOLED;          // alias pooled (dead by then)
    unsigned short* x1 = ws + AGGE;               // alias agg region
    unsigned short* x2 = x1 + (size_t)SZ * 256;
    unsigned short* x3 = x2 + (size_t)SZ * 512;
    float* out_fake = (float*)d_out;
    float* out_x    = out_fake + (size_t)SZ * 64;

    const int SRCr[6] = {0, 1, 0, 2, 2, 1};
    const int DSTr[6] = {1, 0, 2, 0, 1, 2};
    dim3 T(256);

    // ---- prep: weight transposes + Adj conversion (once per launch) ----
    transpose_cvt<<<dim3(4, 4, 6),   T, 0, stream>>>(Wpool[0], nullptr,   ws + P1, 128, 0, 128);
    transpose_cvt<<<dim3(2, 2, 6),   T, 0, stream>>>(Wpool[1], nullptr,   ws + P2, 64, 0, 64);
    transpose_cvt<<<dim3(2, 2, 6),   T, 0, stream>>>(Wpool[2], nullptr,   ws + P3, 64, 0, 64);
    transpose_cvt<<<dim3(8, 2, 6),   T, 0, stream>>>(Wself[0], Wneigh[0], ws + FU1, 128, 128, 64);
    transpose_cvt<<<dim3(4, 2, 6),   T, 0, stream>>>(Wself[1], Wneigh[1], ws + FU2, 64, 64, 64);
    transpose_cvt<<<dim3(4, 2, 6),   T, 0, stream>>>(Wself[2], Wneigh[2], ws + FU3, 64, 64, 64);
    transpose_cvt<<<dim3(130, 8, 1), T, 0, stream>>>(W1, nullptr, ws + W1T, 4160, 0, 256);
    transpose_cvt<<<dim3(8, 16, 1),  T, 0, stream>>>(W2, nullptr, ws + W2T, 256, 0, 512);
    transpose_cvt<<<dim3(16, 32, 1), T, 0, stream>>>(W3, nullptr, ws + W3T, 512, 0, 1024);
    transpose_cvt<<<dim3(32, 128, 1),T, 0, stream>>>(W4, nullptr, ws + W4T, 1024, 0, 4096);
    cvt_f32_bf16<<<16384, T, 0, stream>>>(Adj, ws + ADJ, 4194304);

    // ---- layer 1 (h0 fp32, 128 -> 64) ----
    for (int e = 0; e < 6; ++e) {
        int s = SRCr[e], d = DSTr[e];
        mfma_gemm<1, 1, 1, 0, 0, 0><<<dim3(2, 782), T, 0, stream>>>(
            h0[s], nullptr, ws + P1 + (size_t)e * 16384, bpool[0] + e * 128,
            ws + POOLED, NNODE, 128, 128, 0);
        hipMemsetAsync(agg, 0, (size_t)NNODE * 128 * 4, stream);
        scatter_max_k<128><<<31250, T, 0, stream>>>(
            ws + POOLED, edges + (size_t)e * 2 * NEDGE, edges + (size_t)e * 2 * NEDGE + NEDGE, agg);
        if (e < 3)
            mfma_gemm<1, 1, 0, 0, 0, 0><<<dim3(1, 782), T, 0, stream>>>(
                h0[d], agg, ws + FU1 + (size_t)e * 16384, bself[0] + e * 64,
                ws + HA + (size_t)d * NNODE * 64, NNODE, 64, 128, 128);
        else
            mfma_gemm<1, 1, 0, 0, 1, 0><<<dim3(1, 782), T, 0, stream>>>(
                h0[d], agg, ws + FU1 + (size_t)e * 16384, bself[0] + e * 64,
                ws + HA + (size_t)d * NNODE * 64, NNODE, 64, 128, 128);
    }

    // ---- layers 2,3 (bf16, 64 -> 64) ----
    unsigned short* hin = ws + HA;
    unsigned short* hout = ws + HB;
    for (int layer = 1; layer <= 2; ++layer) {
        const unsigned short* pT = ws + (layer == 1 ? P2 : P3);
        const unsigned short* fT = ws + (layer == 1 ? FU2 : FU3);
        const float* bp = bpool[layer];
        const float* bs_ = bself[layer];
        for (int e = 0; e < 6; ++e) {
            int s = SRCr[e], d = DSTr[e];
            mfma_gemm<0, 1, 1, 0, 0, 0><<<dim3(1, 782), T, 0, stream>>>(
                hin + (size_t)s * NNODE * 64, nullptr, pT + (size_t)e * 4096, bp + e * 64,
                ws + POOLED, NNODE, 64, 64, 0);
            hipMemsetAsync(agg, 0, (size_t)NNODE * 64 * 4, stream);
            scatter_max_k<64><<<15625, T, 0, stream>>>(
                ws + POOLED, edges + (size_t)e * 2 * NEDGE, edges + (size_t)e * 2 * NEDGE + NEDGE, agg);
            if (e < 3)
                mfma_gemm<0, 1, 0, 0, 0, 0><<<dim3(1, 782), T, 0, stream>>>(
                    hin + (size_t)d * NNODE * 64, agg, fT + (size_t)e * 8192, bs_ + e * 64,
                    hout + (size_t)d * NNODE * 64, NNODE, 64, 64, 64);
            else
                mfma_gemm<0, 1, 0, 0, 1, 0><<<dim3(1, 782), T, 0, stream>>>(
                    hin + (size_t)d * NNODE * 64, agg, fT + (size_t)e * 8192, bs_ + e * 64,
                    hout + (size_t)d * NNODE * 64, NNODE, 64, 64, 64);
        }
        unsigned short* tmp = hin; hin = hout; hout = tmp;
    }
    // hin == ws+HA holds h3; mirna = hin (dst type 0)

    fake_k<<<SZ, dim3(64), 0, stream>>>(hin, noise, t_p, left_p, fakef, out_fake);

    // ---- MLP ----
    mfma_gemm<0, 0, 1, 0, 0, 0><<<dim3(4, 64), T, 0, stream>>>(
        ws + ADJ, fakef, ws + W1T, b1, x1, SZ, 256, 4096, 64);
    mfma_gemm<0, 0, 1, 0, 0, 0><<<dim3(8, 64), T, 0, stream>>>(
        x1, nullptr, ws + W2T, b2, x2, SZ, 512, 256, 0);
    mfma_gemm<0, 0, 1, 0, 0, 0><<<dim3(16, 64), T, 0, stream>>>(
        x2, nullptr, ws + W3T, b3, x3, SZ, 1024, 512, 0);
    mfma_gemm<0, 0, 0, 1, 0, 1><<<dim3(64, 64), T, 0, stream>>>(
        x3, nullptr, ws + W4T, b4, out_x, SZ, 4096, 1024, 0);
}

// Round 4
// 1654.558 us; speedup vs baseline: 7.7998x; 7.7998x over previous
//
#include <hip/hip_runtime.h>
#include <hip/hip_bf16.h>

#define NNODE 50000
#define NEDGE 500000
#define SZ    4096

typedef __attribute__((ext_vector_type(8))) short bf16x8;
typedef __attribute__((ext_vector_type(4))) float f32x4;

__device__ __forceinline__ float bits2f(unsigned short u) {
    return __uint_as_float(((unsigned)u) << 16);
}
__device__ __forceinline__ unsigned short f2bits(float f) {  // RNE fp32->bf16
    unsigned x = __float_as_uint(f);
    unsigned r = x + 0x7fffu + ((x >> 16) & 1u);
    return (unsigned short)(r >> 16);
}
__device__ __forceinline__ unsigned pk_max_u16(unsigned a, unsigned b) {
    unsigned lo = max(a & 0xffffu, b & 0xffffu);
    unsigned hi = max(a >> 16, b >> 16);
    return lo | (hi << 16);
}

// ---------------------------------------------------------------------------
// Unified MFMA GEMM. C[M,N] = act( [A1 | A2][M,Ka+Kb] @ B[K,N] + bias (+C) )
// A segments row-major, dtype per DT (0=bf16, 1=fp32); Ka multiple of 64.
// Bt is bf16 PRE-TRANSPOSED [N][K]. Tile 64x64, BK=64, 4 waves.
// ---------------------------------------------------------------------------
template<int DT1, int DT2, int RELU, int SIG, int ACC, int OUTF32>
__global__ __launch_bounds__(256)
void mfma_gemm(const void* __restrict__ A1, const void* __restrict__ A2,
               const unsigned short* __restrict__ Bt, const float* __restrict__ bias,
               void* __restrict__ Cv, int M, int N, int Ka, int Kb)
{
    __shared__ unsigned short As[64][72];
    __shared__ unsigned short Bs[64][72];
    const int tid = threadIdx.x;
    const int wave = tid >> 6, lane = tid & 63;
    const int m16 = lane & 15, quad = lane >> 4;
    const int row0 = blockIdx.y * 64, col0 = blockIdx.x * 64;
    const int K = Ka + Kb;

    f32x4 acc[4] = {};

    for (int k0 = 0; k0 < K; k0 += 64) {
        const bool s2 = (k0 >= Ka);
        const int dt = s2 ? DT2 : DT1;
        const int ld = s2 ? Kb : Ka;
        const int kb = s2 ? (k0 - Ka) : k0;
        if (dt == 0) {
            const unsigned short* src = (const unsigned short*)(s2 ? A2 : A1);
#pragma unroll
            for (int it = 0; it < 2; ++it) {
                int u = tid + it * 256;
                int m = u >> 3, c = (u & 7) * 8;
                int gm = row0 + m;
                uint4 v = make_uint4(0u, 0u, 0u, 0u);
                if (gm < M) v = *(const uint4*)(src + (size_t)gm * ld + kb + c);
                *(uint4*)&As[m][c] = v;
            }
        } else {
            const float* src = (const float*)(s2 ? A2 : A1);
#pragma unroll
            for (int it = 0; it < 4; ++it) {
                int u = tid + it * 256;
                int m = u >> 4, c = (u & 15) * 4;
                int gm = row0 + m;
                float4 v = make_float4(0.f, 0.f, 0.f, 0.f);
                if (gm < M) v = *(const float4*)(src + (size_t)gm * ld + kb + c);
                ushort4 w;
                w.x = f2bits(v.x); w.y = f2bits(v.y); w.z = f2bits(v.z); w.w = f2bits(v.w);
                *(ushort4*)&As[m][c] = w;
            }
        }
#pragma unroll
        for (int it = 0; it < 2; ++it) {
            int u = tid + it * 256;
            int n = u >> 3, c = (u & 7) * 8;
            uint4 v = *(const uint4*)(Bt + (size_t)(col0 + n) * K + k0 + c);
            *(uint4*)&Bs[n][c] = v;
        }
        __syncthreads();
#pragma unroll
        for (int ks = 0; ks < 2; ++ks) {
            bf16x8 a = *(const bf16x8*)&As[wave * 16 + m16][ks * 32 + quad * 8];
#pragma unroll
            for (int nt = 0; nt < 4; ++nt) {
                bf16x8 b = *(const bf16x8*)&Bs[nt * 16 + m16][ks * 32 + quad * 8];
                acc[nt] = __builtin_amdgcn_mfma_f32_16x16x32_bf16(a, b, acc[nt], 0, 0, 0);
            }
        }
        __syncthreads();
    }

#pragma unroll
    for (int nt = 0; nt < 4; ++nt) {
        int gc = col0 + nt * 16 + m16;
        float bv = bias[gc];
#pragma unroll
        for (int r = 0; r < 4; ++r) {
            int gm = row0 + wave * 16 + quad * 4 + r;
            if (gm < M) {
                size_t idx = (size_t)gm * N + gc;
                float v = acc[nt][r] + bv;
                if (ACC) v += OUTF32 ? ((float*)Cv)[idx] : bits2f(((unsigned short*)Cv)[idx]);
                if (RELU) v = fmaxf(v, 0.f);
                if (SIG)  v = 1.f / (1.f + __expf(-v));
                if (OUTF32) ((float*)Cv)[idx] = v;
                else        ((unsigned short*)Cv)[idx] = f2bits(v);
            }
        }
    }
}

// ---------------------------------------------------------------------------
__global__ __launch_bounds__(256)
void transpose_cvt(const float* __restrict__ src1, const float* __restrict__ src2,
                   unsigned short* __restrict__ dst, int R1, int R2, int Nn)
{
    __shared__ float tile[32][33];
    const int R = R1 + R2;
    const int e = blockIdx.z;
    src1 += (size_t)e * R1 * Nn;
    if (src2) src2 += (size_t)e * R2 * Nn;
    dst += (size_t)e * Nn * R;
    const int r0 = blockIdx.x * 32, n0 = blockIdx.y * 32;
    const int lr = threadIdx.x >> 5, ln = threadIdx.x & 31;
#pragma unroll
    for (int i = 0; i < 4; ++i) {
        int r = r0 + lr + i * 8, n = n0 + ln;
        float v = 0.f;
        if (r < R && n < Nn) v = (r < R1) ? src1[(size_t)r * Nn + n]
                                          : src2[(size_t)(r - R1) * Nn + n];
        tile[lr + i * 8][ln] = v;
    }
    __syncthreads();
#pragma unroll
    for (int i = 0; i < 4; ++i) {
        int n = n0 + lr + i * 8, r = r0 + ln;
        if (n < Nn && r < R) dst[(size_t)n * R + r] = f2bits(tile[ln][lr + i * 8]);
    }
}

__global__ __launch_bounds__(256)
void cvt_f32_bf16(const float* __restrict__ src, unsigned short* __restrict__ dst, int n4)
{
    int i = blockIdx.x * 256 + threadIdx.x;
    if (i >= n4) return;
    float4 v = ((const float4*)src)[i];
    ushort4 w;
    w.x = f2bits(v.x); w.y = f2bits(v.y); w.z = f2bits(v.z); w.w = f2bits(v.w);
    ((ushort4*)dst)[i] = w;
}

// ---------------------------------------------------------------------------
// CSR build: histogram of dst, exclusive scan, fill src lists.
// ---------------------------------------------------------------------------
__global__ __launch_bounds__(256)
void hist_k(const int* __restrict__ edges, int* __restrict__ counts)
{
    int r = blockIdx.y;
    int e = blockIdx.x * 256 + threadIdx.x;
    if (e >= NEDGE) return;
    int dst = edges[(size_t)r * 2 * NEDGE + NEDGE + e];
    atomicAdd(&counts[(size_t)r * NNODE + dst], 1);
}

__global__ __launch_bounds__(1024)
void scan_k(const int* __restrict__ counts, int* __restrict__ offs)
{
    const int r = blockIdx.x;
    const int tid = threadIdx.x;
    __shared__ int buf[1024];
    __shared__ int carry_s;
    if (tid == 0) carry_s = 0;
    __syncthreads();
    for (int base = 0; base < NNODE; base += 1024) {
        int idx = base + tid;
        int v = (idx < NNODE) ? counts[(size_t)r * NNODE + idx] : 0;
        buf[tid] = v;
        __syncthreads();
        for (int off = 1; off < 1024; off <<= 1) {
            int t = (tid >= off) ? buf[tid - off] : 0;
            __syncthreads();
            buf[tid] += t;
            __syncthreads();
        }
        if (idx < NNODE) offs[(size_t)r * (NNODE + 1) + idx] = carry_s + buf[tid] - v;
        __syncthreads();
        if (tid == 1023) carry_s += buf[1023];
        __syncthreads();
    }
    if (tid == 0) offs[(size_t)r * (NNODE + 1) + NNODE] = carry_s;
}

__global__ __launch_bounds__(256)
void fill_k(const int* __restrict__ edges, const int* __restrict__ offs,
            int* __restrict__ cursor, int* __restrict__ srcs)
{
    int r = blockIdx.y;
    int e = blockIdx.x * 256 + threadIdx.x;
    if (e >= NEDGE) return;
    int src = edges[(size_t)r * 2 * NEDGE + e];
    int dst = edges[(size_t)r * 2 * NEDGE + NEDGE + e];
    int p = atomicAdd(&cursor[(size_t)r * NNODE + dst], 1);
    srcs[(size_t)r * NEDGE + offs[(size_t)r * (NNODE + 1) + dst] + p] = src;
}

// ---------------------------------------------------------------------------
// segment-max as a gather: thread = (dst node, 8-channel group). Packed u16
// max on raw bf16 bits (valid: relu => all >= 0); acc init 0 implements the
// isneginf->0 rule for isolated nodes. No atomics.
// ---------------------------------------------------------------------------
template<int F>
__global__ __launch_bounds__(256)
void gather_max_k(const unsigned short* __restrict__ pooled,
                  const int* __restrict__ offs, const int* __restrict__ srcs,
                  unsigned short* __restrict__ agg)
{
    const int CG = F / 8;
    int idx = blockIdx.x * 256 + threadIdx.x;
    int n = idx / CG, cg = idx % CG;
    if (n >= NNODE) return;
    int beg = offs[n], end = offs[n + 1];
    unsigned m0 = 0, m1 = 0, m2 = 0, m3 = 0;
    for (int j = beg; j < end; ++j) {
        int s = srcs[j];
        uint4 v = *(const uint4*)(pooled + (size_t)s * F + cg * 8);
        m0 = pk_max_u16(m0, v.x);
        m1 = pk_max_u16(m1, v.y);
        m2 = pk_max_u16(m2, v.z);
        m3 = pk_max_u16(m3, v.w);
    }
    uint4 o; o.x = m0; o.y = m1; o.z = m2; o.w = m3;
    *(uint4*)(agg + (size_t)n * F + cg * 8) = o;
}

__global__ __launch_bounds__(64)
void fake_k(const unsigned short* __restrict__ mirna, const float* __restrict__ noise,
            const int* __restrict__ t_p, const int* __restrict__ left_p,
            unsigned short* __restrict__ fake_bf, float* __restrict__ fake_out)
{
    int r = blockIdx.x, c = threadIdx.x;
    int t = *t_p, left = *left_p;
    int row = left + r;
    float x = bits2f(mirna[(size_t)row * 64 + c]);
    float s = fabsf(x);
#pragma unroll
    for (int off = 32; off > 0; off >>= 1) s += __shfl_down(s, off);
    s = __shfl(s, 0);
    float ab = 1.f;
    for (int i = 0; i <= t; ++i)
        ab *= (1.f - (1e-4f + (0.02f - 1e-4f) * ((float)i / 99.f)));
    float v = sqrtf(ab) * (x / fmaxf(s, 1e-12f)) + sqrtf(1.f - ab) * noise[(size_t)row * 64 + c];
    fake_bf[(size_t)r * 64 + c] = f2bits(v);
    fake_out[(size_t)r * 64 + c] = v;
}

// ---------------------------------------------------------------------------
extern "C" void kernel_launch(void* const* d_in, const int* in_sizes, int n_in,
                              void* d_out, int out_size, void* d_ws, size_t ws_size,
                              hipStream_t stream)
{
    const float* h0[3]    = {(const float*)d_in[0], (const float*)d_in[1], (const float*)d_in[2]};
    const float* Wpool[3] = {(const float*)d_in[3], (const float*)d_in[8],  (const float*)d_in[13]};
    const float* bpool[3] = {(const float*)d_in[4], (const float*)d_in[9],  (const float*)d_in[14]};
    const float* Wself[3] = {(const float*)d_in[5], (const float*)d_in[10], (const float*)d_in[15]};
    const float* bself[3] = {(const float*)d_in[6], (const float*)d_in[11], (const float*)d_in[16]};
    const float* Wneigh[3]= {(const float*)d_in[7], (const float*)d_in[12], (const float*)d_in[17]};
    const float* Adj   = (const float*)d_in[18];
    const float* noise = (const float*)d_in[19];
    const float* W1 = (const float*)d_in[20]; const float* b1 = (const float*)d_in[21];
    const float* W2 = (const float*)d_in[22]; const float* b2 = (const float*)d_in[23];
    const float* W3 = (const float*)d_in[24]; const float* b3 = (const float*)d_in[25];
    const float* W4 = (const float*)d_in[26]; const float* b4 = (const float*)d_in[27];
    const int* edges  = (const int*)d_in[28];
    const int* t_p    = (const int*)d_in[29];
    const int* left_p = (const int*)d_in[31];

    // workspace layout (bf16-element offsets); total ~124.5 MB
    unsigned short* ws = (unsigned short*)d_ws;
    const size_t P1 = 0, P2 = 98304, P3 = 122880;
    const size_t FU1 = 147456, FU2 = 245760, FU3 = 294912;
    const size_t W1T = 344064, W2T = 1409024, W3T = 1540096, W4T = 2064384;
    const size_t ADJ = 6258688;        // 4096*4096 bf16
    const size_t POOLED = 23035904;    // 50000*128 bf16
    const size_t AGGB = 29435904;      // 50000*128 bf16
    const size_t HA = 35835904, HB = 45435904;   // 3*50000*64 bf16 each
    int* counts = (int*)(ws + 55035904);         // 6*50000
    int* offs   = counts + 6 * NNODE;            // 6*(50000+1)
    int* srcs   = offs + 6 * (NNODE + 1);        // 6*500000
    unsigned short* aggb = ws + AGGB;
    // MLP scratch aliases POOLED+AGGB (dead after layer 3):
    unsigned short* x1 = ws + POOLED;
    unsigned short* x2 = x1 + (size_t)SZ * 256;
    unsigned short* x3 = x2 + (size_t)SZ * 512;
    unsigned short* fakef = x3 + (size_t)SZ * 1024;
    float* out_fake = (float*)d_out;
    float* out_x    = out_fake + (size_t)SZ * 64;

    const int SRCr[6] = {0, 1, 0, 2, 2, 1};
    const int DSTr[6] = {1, 0, 2, 0, 1, 2};
    dim3 T(256);

    // ---- prep: weight transposes + Adj conversion ----
    transpose_cvt<<<dim3(4, 4, 6),   T, 0, stream>>>(Wpool[0], nullptr,   ws + P1, 128, 0, 128);
    transpose_cvt<<<dim3(2, 2, 6),   T, 0, stream>>>(Wpool[1], nullptr,   ws + P2, 64, 0, 64);
    transpose_cvt<<<dim3(2, 2, 6),   T, 0, stream>>>(Wpool[2], nullptr,   ws + P3, 64, 0, 64);
    transpose_cvt<<<dim3(8, 2, 6),   T, 0, stream>>>(Wself[0], Wneigh[0], ws + FU1, 128, 128, 64);
    transpose_cvt<<<dim3(4, 2, 6),   T, 0, stream>>>(Wself[1], Wneigh[1], ws + FU2, 64, 64, 64);
    transpose_cvt<<<dim3(4, 2, 6),   T, 0, stream>>>(Wself[2], Wneigh[2], ws + FU3, 64, 64, 64);
    transpose_cvt<<<dim3(130, 8, 1), T, 0, stream>>>(W1, nullptr, ws + W1T, 4160, 0, 256);
    transpose_cvt<<<dim3(8, 16, 1),  T, 0, stream>>>(W2, nullptr, ws + W2T, 256, 0, 512);
    transpose_cvt<<<dim3(16, 32, 1), T, 0, stream>>>(W3, nullptr, ws + W3T, 512, 0, 1024);
    transpose_cvt<<<dim3(32, 128, 1),T, 0, stream>>>(W4, nullptr, ws + W4T, 1024, 0, 4096);
    cvt_f32_bf16<<<16384, T, 0, stream>>>(Adj, ws + ADJ, 4194304);

    // ---- CSR build (edges shared by all 3 layers) ----
    hipMemsetAsync(counts, 0, (size_t)6 * NNODE * 4, stream);
    hist_k<<<dim3(1954, 6), T, 0, stream>>>(edges, counts);
    scan_k<<<6, 1024, 0, stream>>>(counts, offs);
    hipMemsetAsync(counts, 0, (size_t)6 * NNODE * 4, stream);
    fill_k<<<dim3(1954, 6), T, 0, stream>>>(edges, offs, counts, srcs);

    // ---- layer 1 (h0 fp32, 128 -> 64) ----
    for (int e = 0; e < 6; ++e) {
        int s = SRCr[e], d = DSTr[e];
        mfma_gemm<1, 0, 1, 0, 0, 0><<<dim3(2, 782), T, 0, stream>>>(
            h0[s], nullptr, ws + P1 + (size_t)e * 16384, bpool[0] + e * 128,
            ws + POOLED, NNODE, 128, 128, 0);
        gather_max_k<128><<<3125, T, 0, stream>>>(
            ws + POOLED, offs + (size_t)e * (NNODE + 1), srcs + (size_t)e * NEDGE, aggb);
        if (e < 3)
            mfma_gemm<1, 0, 0, 0, 0, 0><<<dim3(1, 782), T, 0, stream>>>(
                h0[d], aggb, ws + FU1 + (size_t)e * 16384, bself[0] + e * 64,
                ws + HA + (size_t)d * NNODE * 64, NNODE, 64, 128, 128);
        else
            mfma_gemm<1, 0, 0, 0, 1, 0><<<dim3(1, 782), T, 0, stream>>>(
                h0[d], aggb, ws + FU1 + (size_t)e * 16384, bself[0] + e * 64,
                ws + HA + (size_t)d * NNODE * 64, NNODE, 64, 128, 128);
    }

    // ---- layers 2,3 (bf16, 64 -> 64) ----
    unsigned short* hin = ws + HA;
    unsigned short* hout = ws + HB;
    for (int layer = 1; layer <= 2; ++layer) {
        const unsigned short* pT = ws + (layer == 1 ? P2 : P3);
        const unsigned short* fT = ws + (layer == 1 ? FU2 : FU3);
        const float* bp = bpool[layer];
        const float* bs_ = bself[layer];
        for (int e = 0; e < 6; ++e) {
            int s = SRCr[e], d = DSTr[e];
            mfma_gemm<0, 0, 1, 0, 0, 0><<<dim3(1, 782), T, 0, stream>>>(
                hin + (size_t)s * NNODE * 64, nullptr, pT + (size_t)e * 4096, bp + e * 64,
                ws + POOLED, NNODE, 64, 64, 0);
            gather_max_k<64><<<1563, T, 0, stream>>>(
                ws + POOLED, offs + (size_t)e * (NNODE + 1), srcs + (size_t)e * NEDGE, aggb);
            if (e < 3)
                mfma_gemm<0, 0, 0, 0, 0, 0><<<dim3(1, 782), T, 0, stream>>>(
                    hin + (size_t)d * NNODE * 64, aggb, fT + (size_t)e * 8192, bs_ + e * 64,
                    hout + (size_t)d * NNODE * 64, NNODE, 64, 64, 64);
            else
                mfma_gemm<0, 0, 0, 0, 1, 0><<<dim3(1, 782), T, 0, stream>>>(
                    hin + (size_t)d * NNODE * 64, aggb, fT + (size_t)e * 8192, bs_ + e * 64,
                    hout + (size_t)d * NNODE * 64, NNODE, 64, 64, 64);
        }
        unsigned short* tmp = hin; hin = hout; hout = tmp;
    }
    // hin == ws+HA holds h3; mirna = hin (dst type 0)

    fake_k<<<SZ, dim3(64), 0, stream>>>(hin, noise, t_p, left_p, fakef, out_fake);

    // ---- MLP ----
    mfma_gemm<0, 0, 1, 0, 0, 0><<<dim3(4, 64), T, 0, stream>>>(
        ws + ADJ, fakef, ws + W1T, b1, x1, SZ, 256, 4096, 64);
    mfma_gemm<0, 0, 1, 0, 0, 0><<<dim3(8, 64), T, 0, stream>>>(
        x1, nullptr, ws + W2T, b2, x2, SZ, 512, 256, 0);
    mfma_gemm<0, 0, 1, 0, 0, 0><<<dim3(16, 64), T, 0, stream>>>(
        x2, nullptr, ws + W3T, b3, x3, SZ, 1024, 512, 0);
    mfma_gemm<0, 0, 0, 1, 0, 1><<<dim3(64, 64), T, 0, stream>>>(
        x3, nullptr, ws + W4T, b4, out_x, SZ, 4096, 1024, 0);
}